// Round 1
// baseline (718.407 us; speedup 1.0000x reference)
//
#include <hip/hip_runtime.h>

// LDS.sampleX: x[t] = A x[t-1] + Q e[t], parallelized via contraction warm-up.
// 8000 chunks x T=125 steps, W=48 warmup (0.82^48 ~ 1e-4 truncation).
// 16 chunks per wave; per step: X_new(64x16) = A*X + Q*E via 16x16x32 bf16 MFMA,
// m=dim (4 tiles), n=chunk, k=dim_in (2 k-steps). State kept as bf16 hi+lo pair
// (compensated) in LDS; output stored from fp32 accumulators.

using bf16x8 = __attribute__((ext_vector_type(8))) short;
using s16x4  = __attribute__((ext_vector_type(4))) short;
using f32x4  = __attribute__((ext_vector_type(4))) float;

#define N_STEPS   1000000
#define XD        64
#define T_CHUNK   125
#define WARM      48
#define N_CHUNKS  (N_STEPS / T_CHUNK)   /* 8000 */
#define N_BLOCKS  (N_CHUNKS / 16)       /* 500  */
#define PAD       72                    /* LDS row stride in bf16 elems (bank spread, 16B-aligned) */

__device__ __forceinline__ short f2bf(float f) {
    unsigned u = __builtin_bit_cast(unsigned, f);
    u += 0x7FFFu + ((u >> 16) & 1u);          // round-to-nearest-even
    return (short)(u >> 16);
}
__device__ __forceinline__ float bf2f(short s) {
    return __builtin_bit_cast(float, ((unsigned)(unsigned short)s) << 16);
}

__global__ __launch_bounds__(64) void lds_scan_kernel(
    const float* __restrict__ eps,   // [N_STEPS, 64]
    const float* __restrict__ A,     // [64, 64] row-major
    const float* __restrict__ Q,     // [64, 64]
    const float* __restrict__ Q0,    // [64, 64]
    const float* __restrict__ x0,    // [64]
    float* __restrict__ out)         // [N_STEPS, 64]
{
    __shared__ short Xh[16 * PAD];   // state hi, [chunk][dim] bf16
    __shared__ short Xl[16 * PAD];   // state lo (residual)
    __shared__ float corr[XD];       // chunk-0 t=0 correction: x0 + (Q0-Q) e0
    __shared__ float e0s[XD];

    const int lane = threadIdx.x;    // 0..63 (one wave per block)
    const int cl   = lane & 15;      // chunk column (n in MFMA B and C/D layouts)
    const int g    = lane >> 4;      // quad index

    // zero initial state
    for (int i = lane; i < 16 * PAD; i += 64) { Xh[i] = 0; Xl[i] = 0; }

    if (blockIdx.x == 0) e0s[lane] = eps[lane];
    __syncthreads();
    if (blockIdx.x == 0) {
        float c = x0[lane];
        #pragma unroll 8
        for (int j = 0; j < XD; ++j)
            c += (Q0[lane * XD + j] - Q[lane * XD + j]) * e0s[j];
        corr[lane] = c;
    }
    __syncthreads();

    // Constant A/Q fragments, MFMA A-operand layout:
    // lane holds M[mt*16 + (lane&15)][ks*32 + (lane>>4)*8 + j], j=0..7
    bf16x8 Af[4][2], Qf[4][2];
    #pragma unroll
    for (int mt = 0; mt < 4; ++mt) {
        #pragma unroll
        for (int ks = 0; ks < 2; ++ks) {
            const float* ap = A + (mt * 16 + cl) * XD + ks * 32 + g * 8;
            const float* qp = Q + (mt * 16 + cl) * XD + ks * 32 + g * 8;
            bf16x8 af, qf;
            #pragma unroll
            for (int j = 0; j < 8; ++j) { af[j] = f2bf(ap[j]); qf[j] = f2bf(qp[j]); }
            Af[mt][ks] = af; Qf[mt][ks] = qf;
        }
    }

    const long chunk = (long)blockIdx.x * 16 + cl;
    const long t0 = chunk * T_CHUNK - WARM;   // negative only for chunk 0
    const int  STOT = WARM + T_CHUNK;
    const int  lx = cl * PAD;

    // eps loads, B-operand layout: lane needs e[t][ks*32 + g*8 + j] (8 floats per ks)
    f32x4 ecur[4], enxt[4];
    {
        const long t  = t0;
        const long ta = t >= 0 ? t : 0;
        const bool v  = t >= 0;
        #pragma unroll
        for (int ks = 0; ks < 2; ++ks)
            #pragma unroll
            for (int h = 0; h < 2; ++h) {
                f32x4 e = ((const f32x4*)(eps + ta * XD + ks * 32 + g * 8))[h];
                ecur[ks * 2 + h] = v ? e : (f32x4){0.f, 0.f, 0.f, 0.f};
            }
    }

    for (int s = 0; s < STOT; ++s) {
        const long t = t0 + s;

        // prefetch next step's eps (independent of state -> hides HBM latency)
        if (s + 1 < STOT) {
            const long tn = t + 1;
            const long ta = tn >= 0 ? tn : 0;
            const bool v  = tn >= 0;
            #pragma unroll
            for (int ks = 0; ks < 2; ++ks)
                #pragma unroll
                for (int h = 0; h < 2; ++h) {
                    f32x4 e = ((const f32x4*)(eps + ta * XD + ks * 32 + g * 8))[h];
                    enxt[ks * 2 + h] = v ? e : (f32x4){0.f, 0.f, 0.f, 0.f};
                }
        }

        // E fragments (fp32 -> bf16)
        bf16x8 ef[2];
        #pragma unroll
        for (int ks = 0; ks < 2; ++ks) {
            bf16x8 e;
            #pragma unroll
            for (int h = 0; h < 2; ++h)
                #pragma unroll
                for (int j = 0; j < 4; ++j)
                    e[h * 4 + j] = f2bf(ecur[ks * 2 + h][j]);
            ef[ks] = e;
        }

        // state fragments from LDS (B-operand layout: 8 consecutive bf16 = ds_read_b128)
        bf16x8 xh0 = *(const bf16x8*)&Xh[lx +  0 + g * 8];
        bf16x8 xh1 = *(const bf16x8*)&Xh[lx + 32 + g * 8];
        bf16x8 xl0 = *(const bf16x8*)&Xl[lx +  0 + g * 8];
        bf16x8 xl1 = *(const bf16x8*)&Xl[lx + 32 + g * 8];

        // X_new = A*(xh + xl) + Q*e, fp32 accumulate
        f32x4 acc[4];
        #pragma unroll
        for (int mt = 0; mt < 4; ++mt) {
            f32x4 a = {0.f, 0.f, 0.f, 0.f};
            a = __builtin_amdgcn_mfma_f32_16x16x32_bf16(Af[mt][0], xh0, a, 0, 0, 0);
            a = __builtin_amdgcn_mfma_f32_16x16x32_bf16(Af[mt][1], xh1, a, 0, 0, 0);
            a = __builtin_amdgcn_mfma_f32_16x16x32_bf16(Af[mt][0], xl0, a, 0, 0, 0);
            a = __builtin_amdgcn_mfma_f32_16x16x32_bf16(Af[mt][1], xl1, a, 0, 0, 0);
            a = __builtin_amdgcn_mfma_f32_16x16x32_bf16(Qf[mt][0], ef[0], a, 0, 0, 0);
            a = __builtin_amdgcn_mfma_f32_16x16x32_bf16(Qf[mt][1], ef[1], a, 0, 0, 0);
            acc[mt] = a;
        }

        // chunk 0, t==0: inject x0 + (Q0 - Q) e0 so result = x0 + Q0 e0 exactly
        if (blockIdx.x == 0 && s == WARM && cl == 0) {
            #pragma unroll
            for (int mt = 0; mt < 4; ++mt)
                #pragma unroll
                for (int r = 0; r < 4; ++r)
                    acc[mt][r] += corr[mt * 16 + g * 4 + r];
        }

        // write back compensated state (C/D layout: lane = chunk cl, dims mt*16+g*4+r)
        #pragma unroll
        for (int mt = 0; mt < 4; ++mt) {
            s16x4 hi, lo;
            #pragma unroll
            for (int r = 0; r < 4; ++r) {
                const float v = acc[mt][r];
                const short h = f2bf(v);
                hi[r] = h;
                lo[r] = f2bf(v - bf2f(h));
            }
            *(s16x4*)&Xh[lx + mt * 16 + g * 4] = hi;
            *(s16x4*)&Xl[lx + mt * 16 + g * 4] = lo;
        }

        // store outputs (fp32, float4 per mt-tile; 4 consecutive dims per lane)
        if (s >= WARM) {
            float* op = out + t * XD;
            #pragma unroll
            for (int mt = 0; mt < 4; ++mt)
                *(f32x4*)(op + mt * 16 + g * 4) = acc[mt];
        }

        #pragma unroll
        for (int i = 0; i < 4; ++i) ecur[i] = enxt[i];
    }
}

extern "C" void kernel_launch(void* const* d_in, const int* in_sizes, int n_in,
                              void* d_out, int out_size, void* d_ws, size_t ws_size,
                              hipStream_t stream) {
    const float* eps = (const float*)d_in[0];   // norm_samp [1e6, 64]
    const float* A   = (const float*)d_in[1];   // [64,64]
    const float* Q   = (const float*)d_in[2];   // QChol [64,64]
    const float* Q0  = (const float*)d_in[3];   // Q0Chol [64,64]
    const float* x0  = (const float*)d_in[4];   // [64]
    float* out = (float*)d_out;

    lds_scan_kernel<<<N_BLOCKS, 64, 0, stream>>>(eps, A, Q, Q0, x0, out);
}

// Round 2
// 466.404 us; speedup vs baseline: 1.5403x; 1.5403x over previous
//
#include <hip/hip_runtime.h>

// LDS.sampleX: x[t] = A x[t-1] + Q e[t], parallelized via contraction warm-up.
// 10000 chunks x T=100 steps, W=28 warmup (0.82^28 ~ 4e-3 worst-case truncation).
// 16 chunks per wave; per step: X_new(64x16) = A*X + Q*E via 16x16x32 bf16 MFMA.
// eps is batch-staged 8 steps at a time: coalesced global loads -> registers
// (held across the previous batch's compute for latency hiding) -> bf16 in LDS.
// State kept as bf16 hi+lo pair (compensated) in LDS; outputs from fp32 accs.

using bf16x8 = __attribute__((ext_vector_type(8))) short;
using s16x4  = __attribute__((ext_vector_type(4))) short;
using f32x4  = __attribute__((ext_vector_type(4))) float;

#define N_STEPS   1000000
#define XD        64
#define T_CHUNK   100
#define WARM      28                    /* divisible by 4 and < B*NB - T */
#define STOT      (WARM + T_CHUNK)      /* 128 = NB*B */
#define BATCH     8
#define NB        (STOT / BATCH)        /* 16 */
#define N_CHUNKS  (N_STEPS / T_CHUNK)   /* 10000 */
#define N_BLOCKS  (N_CHUNKS / 16)       /* 625  */
#define CS        (BATCH * XD + 8)      /* eps LDS chunk stride (bf16 elems), 16B pad -> 2-way banks */
#define PAD       72                    /* state LDS row stride (bf16 elems) */

__device__ __forceinline__ short f2bf(float f) {
    unsigned u = __builtin_bit_cast(unsigned, f);
    u += 0x7FFFu + ((u >> 16) & 1u);          // round-to-nearest-even
    return (short)(u >> 16);
}
__device__ __forceinline__ float bf2f(short s) {
    return __builtin_bit_cast(float, ((unsigned)(unsigned short)s) << 16);
}

__global__ __launch_bounds__(64, 1) void lds_scan_kernel(
    const float* __restrict__ eps,   // [N_STEPS, 64]
    const float* __restrict__ A,     // [64, 64] row-major
    const float* __restrict__ Q,     // [64, 64]
    const float* __restrict__ Q0,    // [64, 64]
    const float* __restrict__ x0,    // [64]
    float* __restrict__ out)         // [N_STEPS, 64]
{
    __shared__ short Eb[16 * CS];    // staged eps, [chunk][step][dim] bf16
    __shared__ short Xh[16 * PAD];   // state hi, [chunk][dim] bf16
    __shared__ short Xl[16 * PAD];   // state lo (residual)
    __shared__ float corr[XD];       // chunk-0 t=0 correction: x0 + (Q0-Q) e0
    __shared__ float e0s[XD];

    const int lane = threadIdx.x;    // 0..63 (one wave per block)
    const int cl   = lane & 15;      // chunk column (n in MFMA B and C/D layouts)
    const int g    = lane >> 4;      // quad index

    // zero initial state
    for (int i = lane; i < 16 * PAD; i += 64) { Xh[i] = 0; Xl[i] = 0; }

    if (blockIdx.x == 0) e0s[lane] = eps[lane];
    __syncthreads();
    if (blockIdx.x == 0) {
        float c = x0[lane];
        #pragma unroll 8
        for (int j = 0; j < XD; ++j)
            c += (Q0[lane * XD + j] - Q[lane * XD + j]) * e0s[j];
        corr[lane] = c;
    }
    __syncthreads();

    // Constant A/Q fragments, MFMA A-operand layout:
    // lane holds M[mt*16 + (lane&15)][ks*32 + (lane>>4)*8 + j], j=0..7
    bf16x8 Af[4][2], Qf[4][2];
    #pragma unroll
    for (int mt = 0; mt < 4; ++mt) {
        #pragma unroll
        for (int ks = 0; ks < 2; ++ks) {
            const float* ap = A + (mt * 16 + cl) * XD + ks * 32 + g * 8;
            const float* qp = Q + (mt * 16 + cl) * XD + ks * 32 + g * 8;
            bf16x8 af, qf;
            #pragma unroll
            for (int j = 0; j < 8; ++j) { af[j] = f2bf(ap[j]); qf[j] = f2bf(qp[j]); }
            Af[mt][ks] = af; Qf[mt][ks] = qf;
        }
    }

    const long chunk  = (long)blockIdx.x * 16 + cl;      // this lane's chunk column
    float* po = out + chunk * ((long)T_CHUNK * XD);      // output base for this chunk

    // --- staging helpers -------------------------------------------------
    // R holds one batch of eps in fp32: [chunk c 0..15][half h2 0..1] of f32x4
    f32x4 R[32];

    // issue coalesced loads for batch b into R (wave-uniform clamp for t<0 rows)
    #define STAGE_LOAD(b)                                                          \
        _Pragma("unroll")                                                          \
        for (int c = 0; c < 16; ++c) {                                             \
            const long tb = ((long)blockIdx.x * 16 + c) * T_CHUNK - WARM + (long)(b) * BATCH; \
            _Pragma("unroll")                                                      \
            for (int h2 = 0; h2 < 2; ++h2) {                                       \
                const long trow = tb + h2 * 4;   /* first of 4 rows, uniform */    \
                if (trow >= 0)                                                     \
                    R[c * 2 + h2] = *(const f32x4*)(eps + trow * XD + lane * 4);   \
                else                                                               \
                    R[c * 2 + h2] = (f32x4){0.f, 0.f, 0.f, 0.f};                   \
            }                                                                      \
        }

    // convert R -> bf16 and write into Eb (conflict-free 8B writes)
    #define STAGE_WRITE()                                                          \
        _Pragma("unroll")                                                          \
        for (int c = 0; c < 16; ++c) {                                             \
            _Pragma("unroll")                                                      \
            for (int h2 = 0; h2 < 2; ++h2) {                                       \
                const f32x4 v = R[c * 2 + h2];                                     \
                s16x4 w;                                                           \
                _Pragma("unroll")                                                  \
                for (int j = 0; j < 4; ++j) w[j] = f2bf(v[j]);                     \
                const int k = h2 * 4 + g;            /* step within batch */       \
                *(s16x4*)&Eb[c * CS + k * XD + cl * 4] = w;                        \
            }                                                                      \
        }
    // ---------------------------------------------------------------------

    STAGE_LOAD(0);
    STAGE_WRITE();

    for (int b = 0; b < NB; ++b) {
        // prefetch next batch into registers; consumed after the 8-step window
        if (b + 1 < NB) { STAGE_LOAD(b + 1); }

        #pragma unroll
        for (int k = 0; k < BATCH; ++k) {
            const int s = b * BATCH + k;

            // E fragments straight from LDS (bf16, B-operand layout)
            bf16x8 ef0 = *(const bf16x8*)&Eb[cl * CS + k * XD +  0 + g * 8];
            bf16x8 ef1 = *(const bf16x8*)&Eb[cl * CS + k * XD + 32 + g * 8];

            // state fragments from LDS
            bf16x8 xh0 = *(const bf16x8*)&Xh[cl * PAD +  0 + g * 8];
            bf16x8 xh1 = *(const bf16x8*)&Xh[cl * PAD + 32 + g * 8];
            bf16x8 xl0 = *(const bf16x8*)&Xl[cl * PAD +  0 + g * 8];
            bf16x8 xl1 = *(const bf16x8*)&Xl[cl * PAD + 32 + g * 8];

            // X_new = A*(xh + xl) + Q*e, fp32 accumulate
            f32x4 acc[4];
            #pragma unroll
            for (int mt = 0; mt < 4; ++mt) {
                f32x4 a = {0.f, 0.f, 0.f, 0.f};
                a = __builtin_amdgcn_mfma_f32_16x16x32_bf16(Af[mt][0], xh0, a, 0, 0, 0);
                a = __builtin_amdgcn_mfma_f32_16x16x32_bf16(Af[mt][1], xh1, a, 0, 0, 0);
                a = __builtin_amdgcn_mfma_f32_16x16x32_bf16(Af[mt][0], xl0, a, 0, 0, 0);
                a = __builtin_amdgcn_mfma_f32_16x16x32_bf16(Af[mt][1], xl1, a, 0, 0, 0);
                a = __builtin_amdgcn_mfma_f32_16x16x32_bf16(Qf[mt][0], ef0, a, 0, 0, 0);
                a = __builtin_amdgcn_mfma_f32_16x16x32_bf16(Qf[mt][1], ef1, a, 0, 0, 0);
                acc[mt] = a;
            }

            // chunk 0, t==0: inject x0 + (Q0 - Q) e0 so result = x0 + Q0 e0
            if (blockIdx.x == 0 && s == WARM && cl == 0) {
                #pragma unroll
                for (int mt = 0; mt < 4; ++mt)
                    #pragma unroll
                    for (int r = 0; r < 4; ++r)
                        acc[mt][r] += corr[mt * 16 + g * 4 + r];
            }

            // write back compensated state (C/D layout: lane=chunk cl, dims mt*16+g*4+r)
            #pragma unroll
            for (int mt = 0; mt < 4; ++mt) {
                s16x4 hi, lo;
                #pragma unroll
                for (int r = 0; r < 4; ++r) {
                    const float v = acc[mt][r];
                    const short h = f2bf(v);
                    hi[r] = h;
                    lo[r] = f2bf(v - bf2f(h));
                }
                *(s16x4*)&Xh[cl * PAD + mt * 16 + g * 4] = hi;
                *(s16x4*)&Xl[cl * PAD + mt * 16 + g * 4] = lo;
            }

            // store outputs (fp32, float4 per mt-tile)
            if (s >= WARM) {
                float* op = po + (long)(s - WARM) * XD;
                #pragma unroll
                for (int mt = 0; mt < 4; ++mt)
                    *(f32x4*)(op + mt * 16 + g * 4) = acc[mt];
            }
        }

        // consume prefetched registers -> LDS for next batch
        if (b + 1 < NB) { STAGE_WRITE(); }
    }
}

extern "C" void kernel_launch(void* const* d_in, const int* in_sizes, int n_in,
                              void* d_out, int out_size, void* d_ws, size_t ws_size,
                              hipStream_t stream) {
    const float* eps = (const float*)d_in[0];   // norm_samp [1e6, 64]
    const float* A   = (const float*)d_in[1];   // [64,64]
    const float* Q   = (const float*)d_in[2];   // QChol [64,64]
    const float* Q0  = (const float*)d_in[3];   // Q0Chol [64,64]
    const float* x0  = (const float*)d_in[4];   // [64]
    float* out = (float*)d_out;

    lds_scan_kernel<<<N_BLOCKS, 64, 0, stream>>>(eps, A, Q, Q0, x0, out);
}